// Round 7
// baseline (180.624 us; speedup 1.0000x reference)
//
#include <hip/hip_runtime.h>

// RoiCut: out[i, c, y, x] = fm[assoc[i], c, y0_i + y, x0_i + x]
// fm: [8, 256, 200, 200] fp32, boxes_yx: [512, 2] int32 (y0, x0), assoc: [512] int32
// out: [512, 256, 32, 32] fp32
//
// R6 strategy: break device-wide phase lock so reads and writes mix at the HBM.
//  - block = (sample, channel, quarter): 50 rows = 40,000 B static LDS, 512 thr
//    -> 4 blocks/CU x 8 waves = 32 waves/CU, variable-length box lists
//    -> blocks drift out of phase -> concurrent read+write streams (copy-like).
//  - group kernel bins boxes into 32 (sample, quarter) lists; a box straddling
//    a quarter boundary appears in both lists, row-predicated so each output
//    row is written exactly once.
//  - reads exact-once & perfectly coalesced; non-temporal dwordx4 stores.

typedef float v4f __attribute__((ext_vector_type(4)));

constexpr int C_     = 256;
constexpr int H_     = 200;
constexpr int W_     = 200;
constexpr int BOX_   = 32;
constexpr int N_     = 512;
constexpr int B_     = 8;
constexpr int PLANE  = H_ * W_;        // 40000 floats
constexpr int QROWS  = 50;             // rows per quarter
constexpr int NQ     = 4;
constexpr int NBIN   = B_ * NQ;        // 32 (sample, quarter) bins
constexpr int QLDS   = QROWS * W_;     // 10000 floats = 40,000 B
constexpr int QLDS4  = QLDS / 4;       // 2500 float4

__global__ __launch_bounds__(512) void group_boxes_kernel(
    const int* __restrict__ boxes,
    const int* __restrict__ assoc,
    unsigned int* __restrict__ keys,
    int* __restrict__ starts)
{
    __shared__ int cnt[NBIN];
    __shared__ int base[NBIN + 1];
    int t = threadIdx.x;   // 512 threads, one per box

    if (t < NBIN) cnt[t] = 0;
    __syncthreads();

    int y0 = boxes[2 * t];
    int x0 = boxes[2 * t + 1];
    y0 = min(max(y0, 0), H_ - BOX_);
    x0 = min(max(x0, 0), W_ - BOX_);
    int a = assoc[t];
    // key: [y0:8 | x0:8 | idx:9]
    unsigned int key = ((unsigned int)y0 << 17) | ((unsigned int)x0 << 9) | (unsigned int)t;

    int q0 = y0 / QROWS;                  // first quarter touched
    int q1 = (y0 + BOX_ - 1) / QROWS;     // last quarter touched (q0 or q0+1)
    int bin0 = a * NQ + q0;
    int p0 = atomicAdd(&cnt[bin0], 1);    // order nondeterminism benign (disjoint outputs)
    int bin1 = -1, p1 = -1;
    if (q1 != q0) {
        bin1 = a * NQ + q1;
        p1 = atomicAdd(&cnt[bin1], 1);
    }
    __syncthreads();

    if (t == 0) {
        int s = 0;
        for (int i = 0; i < NBIN; ++i) { base[i] = s; s += cnt[i]; }
        base[NBIN] = s;
    }
    __syncthreads();

    keys[base[bin0] + p0] = key;
    if (p1 >= 0) keys[base[bin1] + p1] = key;
    if (t <= NBIN) starts[t] = base[t];
}

__global__ __launch_bounds__(512, 8) void roicut_kernel(
    const float* __restrict__ fm,
    const unsigned int* __restrict__ keys,
    const int* __restrict__ starts,
    float* __restrict__ out)
{
    __shared__ float lds[QLDS];    // 40,000 B = 50 rows x 200

    int bid = blockIdx.x;
    int qtr = bid & 3;             // quarter: rows [50*qtr, 50*qtr+50)
    int c   = (bid >> 2) & 255;    // channel
    int a   = bid >> 10;           // sample
    int t   = threadIdx.x;         // 512 threads

    int bin = a * NQ + qtr;
    int b0 = starts[bin], b1 = starts[bin + 1];
    if (b0 == b1) return;          // empty bin: skip staging entirely

    // ---- stage quarter plane into LDS, perfectly coalesced, exact-once ----
    const v4f* src = (const v4f*)(fm + (size_t)(a * C_ + c) * PLANE) + qtr * QLDS4;
    v4f* l4 = (v4f*)lds;
    v4f r0 = src[t];
    v4f r1 = src[t + 512];
    v4f r2 = src[t + 1024];
    v4f r3 = src[t + 1536];
    bool tail = t < (QLDS4 - 2048);   // t < 452
    v4f r4;
    if (tail) r4 = src[t + 2048];
    l4[t]        = r0;
    l4[t + 512]  = r1;
    l4[t + 1024] = r2;
    l4[t + 1536] = r3;
    if (tail) l4[t + 2048] = r4;
    __syncthreads();

    // ---- box loop: 2 boxes in flight (sub = 4 waves each) ----
    int sub   = t >> 8;            // 0..1
    int q     = t & 255;           // pixel-quad within box tile
    int y     = q >> 3;            // 0..31
    int xg    = (q & 7) << 2;      // 0,4,...,28
    int rbase = qtr * QROWS;       // first plane row owned by this quarter

    for (int b = b0; b < b1; b += 2) {
        int bb = b + sub;
        if (bb < b1) {
            unsigned int v = keys[bb];
            int y0 = (v >> 17) & 255;
            int x0 = (v >> 9) & 255;
            int i  = (int)(v & 511u);
            int ly = y0 + y - rbase;          // row within this quarter
            if (ly >= 0 && ly < QROWS) {      // predicated rows (straddling boxes)
                const float* p = lds + ly * W_ + (x0 + xg);
                v4f vv;
                vv[0] = p[0]; vv[1] = p[1]; vv[2] = p[2]; vv[3] = p[3];
                v4f* dst = (v4f*)(out + (((size_t)i << 18) + ((size_t)c << 10) + (size_t)(q << 2)));
                __builtin_nontemporal_store(vv, dst);
            }
        }
    }
}

extern "C" void kernel_launch(void* const* d_in, const int* in_sizes, int n_in,
                              void* d_out, int out_size, void* d_ws, size_t ws_size,
                              hipStream_t stream) {
    const float* fm    = (const float*)d_in[0];
    const int*   boxes = (const int*)d_in[1];
    const int*   assoc = (const int*)d_in[2];
    float*       out   = (float*)d_out;

    unsigned int* keys   = (unsigned int*)d_ws;          // <= 1024 u32
    int*          starts = (int*)d_ws + 2 * N_;          // 33 ints

    group_boxes_kernel<<<1, N_, 0, stream>>>(boxes, assoc, keys, starts);

    int grid = B_ * C_ * NQ;   // 8192 blocks: one per (sample, channel, quarter)
    roicut_kernel<<<grid, 512, 0, stream>>>(fm, keys, starts, out);
}